// Round 5
// baseline (340.329 us; speedup 1.0000x reference)
//
#include <hip/hip_runtime.h>
#include <math.h>

#define NJ 17
#define NP 14
#define NCH 59     // 17 + 3*14
#define BATCH 256
#define PSTRIDE 64 // padded partial-row stride (floats) for aligned float4

__constant__ int c_par0[NP] = {0, 1, 2, 0, 4, 5, 0, 8, 14, 15, 8, 11, 12, 8};
__constant__ int c_par1[NP] = {1, 2, 3, 4, 5, 6, 8, 14, 15, 16, 11, 12, 13, 10};

__device__ __forceinline__ float wave_reduce(float v) {
    #pragma unroll
    for (int off = 32; off; off >>= 1) v += __shfl_down(v, off, 64);
    return v;
}

// Normalized heatmap h = exp(-0.25*(dx^2+dy^2-m)), m = d2 at clamped nearest
// integer grid point (== grid max of the gaussian, closed form).
__device__ __forceinline__ void heat_params(const float* __restrict__ joint2d,
                                            int b, int j,
                                            float& x, float& y, float& m) {
    x = joint2d[(b * NJ + j) * 2 + 0] * 64.f;
    y = joint2d[(b * NJ + j) * 2 + 1] * 64.f;
    const float rx = fminf(fmaxf(floorf(x + 0.5f), 0.f), 63.f);
    const float ry = fminf(fmaxf(floorf(y + 0.5f), 0.f), 63.f);
    m = (rx - x) * (rx - x) + (ry - y) * (ry - y);
}

// Wave-per-slice: grid (59, 64) x 256 threads; wave w of block (c, by) owns
// slice (b = 4*by + w, c). 16 float4 loads per lane all in flight, no LDS,
// no __syncthreads. Lane's 4 columns are j-invariant; rows = (lane>>4) + 4j.
__global__ __launch_bounds__(256) void slice_sum_kernel(
    const float* __restrict__ pred,     // [B,17,3]
    const float* __restrict__ joints,   // [B,17,3]
    const float* __restrict__ middle,   // [B,59,64,64]
    const float* __restrict__ joint2d,  // [B,17,2]
    float* __restrict__ partial)        // [B,PSTRIDE]: c=0..58 slices, 59=l3d
{
    const int c    = blockIdx.x;            // 0..58
    const int lane = threadIdx.x & 63;
    const int b    = (blockIdx.y << 2) | (threadIdx.x >> 6);  // 0..255

    // ---- issue all 16 slice loads immediately (256 B/lane in flight) ----
    const float4* __restrict__ src =
        (const float4*)(middle + ((size_t)b * NCH + c) * 4096) + lane;
    float4 d[16];
    #pragma unroll
    for (int j = 0; j < 16; ++j) d[j] = src[64 * j];

    // ---- wave-uniform target setup ----
    float wp = 0.f, wc = 0.f;
    int jp = 0, jc = 0;
    if (c < NJ) {
        jp = c; wp = 1.f;
    } else {
        const int pi = c - NJ;
        const int p  = pi / 3;
        const int ch = pi - p * 3;
        jp = c_par0[p];
        jc = c_par1[p];
        const float dz = joints[(b * NJ + jp) * 3 + 2] - joints[(b * NJ + jc) * 3 + 2];
        const int rs = (dz > 0.1f) ? 1 : ((fabsf(dz) < 0.1f) ? 0 : -1);
        if (ch == 0)      { wp = 0.f; wc = (rs == -1) ? 1.f : 0.f; }
        else if (ch == 1) { wp = 1.f; wc = (rs ==  0) ? 1.f : 0.f; }
        else              { wp = 0.f; wc = (rs ==  1) ? 1.f : 0.f; }
    }

    float xp = 0.f, yp = 0.f, mp = 0.f;
    float xq = 0.f, yq = 0.f, mq = 0.f;
    if (wp != 0.f) heat_params(joint2d, b, jp, xp, yp, mp);
    if (wc != 0.f) heat_params(joint2d, b, jc, xq, yq, mq);

    // ---- separable gaussian: 4 fixed columns per lane, rows r0 + 4j ----
    const float col0 = (float)((4 * lane) & 63);
    const float row0 = (float)(lane >> 4);       // 0..3
    float cEp[4] = {0.f, 0.f, 0.f, 0.f};
    float cEc[4] = {0.f, 0.f, 0.f, 0.f};
    if (wp != 0.f) {
        #pragma unroll
        for (int q = 0; q < 4; ++q) {
            const float dy = (col0 + (float)q) - yp;
            cEp[q] = __expf(-0.25f * dy * dy);
        }
    }
    if (wc != 0.f) {
        #pragma unroll
        for (int q = 0; q < 4; ++q) {
            const float dy = (col0 + (float)q) - yq;
            cEc[q] = __expf(-0.25f * dy * dy);
        }
    }
    const float mp4 = 0.25f * mp;
    const float mq4 = 0.25f * mq;

    float acc = 0.f;
    #pragma unroll
    for (int j = 0; j < 16; ++j) {
        const float fi = row0 + (float)(4 * j);
        float rEp = 0.f, rEc = 0.f;
        if (wp != 0.f) {  // wave-uniform
            const float dx = fi - xp;
            rEp = __expf(fmaf(-0.25f * dx, dx, mp4));
        }
        if (wc != 0.f) {  // wave-uniform
            const float dx = fi - xq;
            rEc = __expf(fmaf(-0.25f * dx, dx, mq4));
        }
        const float mv[4] = {d[j].x, d[j].y, d[j].z, d[j].w};
        #pragma unroll
        for (int q = 0; q < 4; ++q) {
            const float tgt = fmaf(rEc, cEc[q], rEp * cEp[q]);
            const float df = tgt - mv[q];
            acc = fmaf(df, df, acc);
        }
    }

    acc = wave_reduce(acc);
    if (lane == 0) partial[b * PSTRIDE + c] = acc;

    // ---- l3d row (c==0 waves; 51 values per batch row) ----
    if (c == 0) {
        float v = 0.f;
        if (lane < NJ * 3) {
            const int i = b * NJ * 3 + lane;
            v = fabsf(joints[i] - pred[i]);
        }
        v = wave_reduce(v);
        if (lane == 0) partial[b * PSTRIDE + 59] = v;
    }
}

// One block, 256 threads: thread b reduces batch row b (60 floats, 15 aligned
// float4 loads), then cross-thread double reduction. No atomics, no memset.
__global__ __launch_bounds__(256) void finalize_kernel(
    const float* __restrict__ partial,  // [B,PSTRIDE]
    float* __restrict__ out)            // [1]
{
    const int b = threadIdx.x;
    const float4* __restrict__ row = (const float4*)(partial + b * PSTRIDE);
    float4 r[15];
    #pragma unroll
    for (int i = 0; i < 15; ++i) r[i] = row[i];
    const float* pr = (const float*)r;

    float l2d = 0.f;
    #pragma unroll
    for (int c = 0; c < NJ; ++c) l2d += pr[c];

    float hem = 0.f;
    #pragma unroll
    for (int p = 0; p < NP; ++p) {
        const float n = sqrtf(pr[NJ + 3 * p + 0]) +
                        sqrtf(pr[NJ + 3 * p + 1]) +
                        sqrtf(pr[NJ + 3 * p + 2]);
        hem = fmaf(n, n, hem);
    }

    double v = ((double)pr[59] + 0.005 * ((double)l2d + (double)hem)) * (1.0 / BATCH);

    #pragma unroll
    for (int off = 32; off; off >>= 1) v += __shfl_down(v, off, 64);
    __shared__ double sh[4];
    if ((b & 63) == 0) sh[b >> 6] = v;
    __syncthreads();
    if (b == 0) out[0] = (float)(sh[0] + sh[1] + sh[2] + sh[3]);
}

extern "C" void kernel_launch(void* const* d_in, const int* in_sizes, int n_in,
                              void* d_out, int out_size, void* d_ws, size_t ws_size,
                              hipStream_t stream) {
    const float* pred    = (const float*)d_in[0];
    const float* joints  = (const float*)d_in[1];
    const float* middle  = (const float*)d_in[2];
    const float* joint2d = (const float*)d_in[3];
    float* out  = (float*)d_out;
    float* part = (float*)d_ws;   // BATCH*PSTRIDE floats, fully written before read

    dim3 grid(NCH, BATCH / 4);
    slice_sum_kernel<<<grid, 256, 0, stream>>>(pred, joints, middle, joint2d, part);
    finalize_kernel<<<1, 256, 0, stream>>>(part, out);
}